// Round 7
// baseline (2081.686 us; speedup 1.0000x reference)
//
#include <hip/hip_runtime.h>
#include <hip/hip_bf16.h>

#define NPIX 4096
#define CCH  256
#define HID  64
#define BAT  4
#define XSTR 264    // proj LDS row stride (halfs)
#define PTS  136    // attn P-tile row stride (halfs): 16B-aligned rows

using f32x4 = __attribute__((ext_vector_type(4))) float;
using h16x8 = __attribute__((ext_vector_type(8))) _Float16;
using u16x4 = __attribute__((ext_vector_type(4))) unsigned short;

#define L2E 1.44269504088896340736f

__device__ __forceinline__ unsigned short f2h(float f) {
    _Float16 h = (_Float16)f;
    return __builtin_bit_cast(unsigned short, h);
}
__device__ __forceinline__ h16x8 ldg_fragh(const unsigned short* p) {
    uint4 v = *reinterpret_cast<const uint4*>(p);
    return __builtin_bit_cast(h16x8, v);
}
__device__ __forceinline__ h16x8 lds_fragh(const unsigned short* p) {
    return *reinterpret_cast<const h16x8*>(p);
}
__device__ __forceinline__ unsigned int pk2h(float a, float b) {
    auto t = __builtin_amdgcn_cvt_pkrtz(a, b);   // <2 x half>, RTZ
    return __builtin_bit_cast(unsigned int, t);
}
__device__ __forceinline__ float sel4(float a0, float a1, float a2, float a3, int q) {
    float x = (q & 1) ? a1 : a0;
    float y = (q & 1) ? a3 : a2;
    return (q & 2) ? y : x;
}

// ---------------------------------------------------------------------------
// W conversion -> row-major [384][256] fp16. Rows 0-63: Wq pre-scaled by
// log2(e) (softmax uses exp2), 64-127: Wk, 128-383: Wv.
// ---------------------------------------------------------------------------
__global__ __launch_bounds__(256, 1) void wcvt_kernel(
    const float* __restrict__ Wq, const float* __restrict__ Wk,
    const float* __restrict__ Wv, unsigned short* __restrict__ Wg)
{
    int idx = (blockIdx.x * 256 + threadIdx.x) * 4;
    int r = idx >> 8, c = idx & 255;
    const float* src = (r < 64)  ? (Wq + r * CCH + c)
                     : (r < 128) ? (Wk + (r - 64) * CCH + c)
                                 : (Wv + (r - 128) * CCH + c);
    float sc = (r < 64) ? L2E : 1.0f;
    float4 v4 = *reinterpret_cast<const float4*>(src);
    u16x4 hv;
    hv[0] = f2h(v4.x * sc); hv[1] = f2h(v4.y * sc);
    hv[2] = f2h(v4.z * sc); hv[3] = f2h(v4.w * sc);
    *reinterpret_cast<u16x4*>(Wg + idx) = hv;
}

// ---------------------------------------------------------------------------
// fp16 MFMA projection (round-5-proven numerics/stores, W dbuf kept).
// Q/K fp16 [n][h]; V fp16 [c][n]. Scratch transposes use explicit waitcnt
// (cross-lane LDS RAW within a wave) exactly as the passing round-5 kernel.
// ---------------------------------------------------------------------------
__global__ __launch_bounds__(256, 2) void proj_kernel(
    const float* __restrict__ x1, const float* __restrict__ x2,
    const unsigned short* __restrict__ Wg,
    const float* __restrict__ bq, const float* __restrict__ bk,
    const float* __restrict__ bv,
    unsigned short* __restrict__ Qf, unsigned short* __restrict__ Kf,
    unsigned short* __restrict__ Vt)
{
    __shared__ unsigned short xs[32][XSTR];
    __shared__ unsigned short scratch[4][256];

    const int Lb = blockIdx.x;
    const int sb = Lb & 7;              // XCD-locality swizzle
    const int tile = Lb >> 3;
    const int s = sb >> 2, b = sb & 3;
    const float* x = s ? x2 : x1;
    const int n0 = tile * 32;
    const int t = threadIdx.x;
    const int lane = t & 63;
    const int w = __builtin_amdgcn_readfirstlane(t >> 6);
    const int quad = lane >> 4, lq = lane & 15;

    // stage x^T fp16 into LDS
    {
        const int n = t & 31;
        const int g = t >> 5;
        const float* xb = x + (size_t)(b * CCH) * NPIX + n0;
        #pragma unroll
        for (int i = 0; i < 8; ++i) {
            int c0 = g * 4 + i * 32;
            u16x4 hv;
            #pragma unroll
            for (int j = 0; j < 4; ++j)
                hv[j] = f2h(xb[(size_t)(c0 + j) * NPIX + n]);
            *reinterpret_cast<u16x4*>(&xs[n][c0]) = hv;
        }
    }
    __syncthreads();

    // hoist x fragments (both ntiles, full K=256)
    h16x8 xf[2][8];
    #pragma unroll
    for (int nt = 0; nt < 2; ++nt)
        #pragma unroll
        for (int ks = 0; ks < 8; ++ks)
            xf[nt][ks] = lds_fragh(&xs[nt * 16 + lq][ks * 32 + quad * 8]);

    const int sbN = (s * BAT + b) * NPIX;
    const int sbC = (s * BAT + b) * CCH;
    unsigned short* sc = scratch[w];

    // W fragment double-buffer
    h16x8 wf[2][8];
    {
        const unsigned short* wp = Wg + (size_t)((w * 6) * 16 + lq) * CCH + quad * 8;
        #pragma unroll
        for (int ks = 0; ks < 8; ++ks) wf[0][ks] = ldg_fragh(wp + ks * 32);
    }

    for (int hloop = 0; hloop < 6; ++hloop) {
        const int cur = hloop & 1;
        const int idx = w * 6 + hloop;                  // wave-uniform, 0..23
        const int kind = idx < 4 ? 0 : (idx < 8 ? 1 : 2);

        if (hloop < 5) {
            const unsigned short* wp = Wg + (size_t)((idx + 1) * 16 + lq) * CCH + quad * 8;
            #pragma unroll
            for (int ks = 0; ks < 8; ++ks) wf[cur ^ 1][ks] = ldg_fragh(wp + ks * 32);
        }

        #pragma unroll
        for (int nt = 0; nt < 2; ++nt) {
            f32x4 acc = (f32x4){0.f, 0.f, 0.f, 0.f};
            if (kind == 2) {
                #pragma unroll
                for (int ks = 0; ks < 8; ++ks)
                    acc = __builtin_amdgcn_mfma_f32_16x16x32_f16(wf[cur][ks], xf[nt][ks], acc, 0, 0, 0);
                // D[c][n] -> scratch -> coalesced fp16 store
                int cbase = (idx - 8) * 16;
                #pragma unroll
                for (int reg = 0; reg < 4; ++reg)
                    sc[(quad * 4 + reg) * 16 + lq] = f2h(acc[reg] + bv[cbase + quad * 4 + reg]);
                int rl = lane >> 2, c0 = (lane & 3) * 4;
                __builtin_amdgcn_s_waitcnt(0);   // cross-lane LDS RAW (round-5-proven)
                unsigned long long v = *reinterpret_cast<const unsigned long long*>(&sc[rl * 16 + c0]);
                *reinterpret_cast<unsigned long long*>(
                    &Vt[(size_t)(sbC + cbase + rl) * NPIX + n0 + nt * 16 + c0]) = v;
            } else {
                #pragma unroll
                for (int ks = 0; ks < 8; ++ks)
                    acc = __builtin_amdgcn_mfma_f32_16x16x32_f16(xf[nt][ks], wf[cur][ks], acc, 0, 0, 0);
                // D[n][h] -> scratch -> coalesced fp16 store
                unsigned short* dq = (kind ? Kf : Qf);
                const float* bias = (kind ? bk : bq);
                int hbase = (kind ? (idx - 4) : idx) * 16;
                float bb = bias[hbase + lq] * (kind ? 1.0f : L2E);
                #pragma unroll
                for (int reg = 0; reg < 4; ++reg)
                    sc[(quad * 4 + reg) * 16 + lq] = f2h(acc[reg] + bb);
                int rl = lane >> 2, h0 = (lane & 3) * 4;
                __builtin_amdgcn_s_waitcnt(0);
                unsigned long long v = *reinterpret_cast<const unsigned long long*>(&sc[rl * 16 + h0]);
                *reinterpret_cast<unsigned long long*>(
                    &dq[(size_t)(sbN + n0 + nt * 16 + rl) * HID + hbase + h0]) = v;
            }
        }
    }
}

// ---------------------------------------------------------------------------
// Score-max kernel: Mg[db][n] = max_m S'[n][m], S' = (K Q^T) in exp2 units.
// Same fragment loads and an IDENTICAL MFMA nest as attn's S-phase, so the
// S values match bitwise and attn's P = exp2(S - M) <= 1 exactly.
// No barriers in the loop: pure MFMA + register fmax; K double-buffered.
// ---------------------------------------------------------------------------
__global__ __launch_bounds__(256, 2) void smax_kernel(
    const unsigned short* __restrict__ Qf, const unsigned short* __restrict__ Kf,
    float* __restrict__ Mg)
{
    __shared__ float Msh[4][64];

    const int Lb = blockIdx.x;
    const int g = Lb & 7;
    const int ntile = Lb >> 3;
    const int d = g >> 2, b = g & 3;
    const int db = d * BAT + b;
    const int s = d, r = 1 - d;
    const int n0 = ntile * 64;

    const int t = threadIdx.x;
    const int lane = t & 63;
    const int w = __builtin_amdgcn_readfirstlane(t >> 6);
    const int quad = lane >> 4, lq = lane & 15;

    const unsigned short* Qb = Qf + (size_t)(s * BAT + b) * NPIX * HID;
    const unsigned short* Kb = Kf + (size_t)(r * BAT + b) * NPIX * HID;

    h16x8 qf[4][2];
    #pragma unroll
    for (int nt = 0; nt < 4; ++nt)
        #pragma unroll
        for (int ks = 0; ks < 2; ++ks)
            qf[nt][ks] = ldg_fragh(Qb + (n0 + nt * 16 + lq) * HID + ks * 32 + quad * 8);

    h16x8 kf[2][2][2];
    #pragma unroll
    for (int mt = 0; mt < 2; ++mt)
        #pragma unroll
        for (int ks = 0; ks < 2; ++ks)
            kf[0][mt][ks] = ldg_fragh(Kb + (w * 32 + mt * 16 + lq) * HID + ks * 32 + quad * 8);

    float mx[4] = {-3.0e38f, -3.0e38f, -3.0e38f, -3.0e38f};

    for (int it = 0; it < 32; ++it) {
        const int cur = it & 1;
        if (it < 31) {
            #pragma unroll
            for (int mt = 0; mt < 2; ++mt)
                #pragma unroll
                for (int ks = 0; ks < 2; ++ks)
                    kf[cur ^ 1][mt][ks] = ldg_fragh(
                        Kb + ((it + 1) * 128 + w * 32 + mt * 16 + lq) * HID + ks * 32 + quad * 8);
        }
        f32x4 Sacc[2][4];
        #pragma unroll
        for (int mt = 0; mt < 2; ++mt)
            #pragma unroll
            for (int nt = 0; nt < 4; ++nt)
                Sacc[mt][nt] = (f32x4){0.f, 0.f, 0.f, 0.f};
        #pragma unroll
        for (int mt = 0; mt < 2; ++mt)
            #pragma unroll
            for (int ks = 0; ks < 2; ++ks)
                #pragma unroll
                for (int nt = 0; nt < 4; ++nt)
                    Sacc[mt][nt] = __builtin_amdgcn_mfma_f32_16x16x32_f16(
                        kf[cur][mt][ks], qf[nt][ks], Sacc[mt][nt], 0, 0, 0);
        #pragma unroll
        for (int mt = 0; mt < 2; ++mt)
            #pragma unroll
            for (int nt = 0; nt < 4; ++nt)
                mx[nt] = fmaxf(mx[nt],
                               fmaxf(fmaxf(Sacc[mt][nt][0], Sacc[mt][nt][1]),
                                     fmaxf(Sacc[mt][nt][2], Sacc[mt][nt][3])));
    }

    #pragma unroll
    for (int nt = 0; nt < 4; ++nt) {
        mx[nt] = fmaxf(mx[nt], __shfl_xor(mx[nt], 16));
        mx[nt] = fmaxf(mx[nt], __shfl_xor(mx[nt], 32));
    }
    Msh[w][quad * 16 + lq] = sel4(mx[0], mx[1], mx[2], mx[3], quad);
    __syncthreads();

    if (t < 64) {
        float m = fmaxf(fmaxf(Msh[0][t], Msh[1][t]), fmaxf(Msh[2][t], Msh[3][t]));
        Mg[(size_t)db * NPIX + n0 + t] = m;
    }
}

// ---------------------------------------------------------------------------
// Flash cross-attention v7: precomputed-max softmax. P = exp2(S - M[n]) <= 1
// exactly (M from smax_kernel, bitwise-identical S). No online-softmax logic
// at all: no running max, no rescale, no cross-wave exchange. Per 128-m iter:
// S fp16-MFMA -> exp2 -> P(fp16) to double-buffered LDS -> ONE barrier ->
// PV fp16-MFMA; K(it+1)/V loads issue strictly post-barrier.
// ---------------------------------------------------------------------------
__global__ __launch_bounds__(256, 2) void attn_kernel(
    const float* __restrict__ x1, const float* __restrict__ x2,
    const unsigned short* __restrict__ Qf, const unsigned short* __restrict__ Kf,
    const unsigned short* __restrict__ Vt,
    const float* __restrict__ Mg, const float* __restrict__ gamma,
    float* __restrict__ out)
{
    __shared__ unsigned short PT[2][64 * PTS];   // P^T [n=64][m=128], fp16, dbuf
    __shared__ float Lsh[4][64];

    const int Lb = blockIdx.x;
    const int g = Lb & 7;                        // XCD-locality swizzle
    const int ntile = Lb >> 3;
    const int d = g >> 2, b = g & 3;
    const int db = d * BAT + b;
    const int s = d, r = 1 - d;
    const int n0 = ntile * 64;

    const int t = threadIdx.x;
    const int lane = t & 63;
    const int w = __builtin_amdgcn_readfirstlane(t >> 6);
    const int quad = lane >> 4, lq = lane & 15;

    const unsigned short* Qb = Qf + (size_t)(s * BAT + b) * NPIX * HID;
    const unsigned short* Kb = Kf + (size_t)(r * BAT + b) * NPIX * HID;
    const unsigned short* Vb = Vt + (size_t)(r * BAT + b) * CCH * NPIX;

    // per-column max (exp2 units), computed by smax_kernel
    float Mn[4];
    #pragma unroll
    for (int nt = 0; nt < 4; ++nt)
        Mn[nt] = Mg[(size_t)db * NPIX + n0 + nt * 16 + lq];

    // Q fragments, persistent (B-frags)
    h16x8 qf[4][2];
    #pragma unroll
    for (int nt = 0; nt < 4; ++nt)
        #pragma unroll
        for (int ks = 0; ks < 2; ++ks)
            qf[nt][ks] = ldg_fragh(Qb + (n0 + nt * 16 + lq) * HID + ks * 32 + quad * 8);

    f32x4 Oacc[4][4];
    #pragma unroll
    for (int rt = 0; rt < 4; ++rt)
        #pragma unroll
        for (int ct = 0; ct < 4; ++ct)
            Oacc[rt][ct] = (f32x4){0.f, 0.f, 0.f, 0.f};

    float Li[4] = {0.f, 0.f, 0.f, 0.f};

    // K(0) fragments (wave owns 32 m-rows per 128-m iter)
    h16x8 kf[2][2];
    #pragma unroll
    for (int mt = 0; mt < 2; ++mt)
        #pragma unroll
        for (int ks = 0; ks < 2; ++ks)
            kf[mt][ks] = ldg_fragh(Kb + (w * 32 + mt * 16 + lq) * HID + ks * 32 + quad * 8);

    for (int it = 0; it < 32; ++it) {
        const int buf = it & 1;
        const int m0 = it * 128;

        // ---- S phase: S^T[wave's 32 m][64 n], fp16 MFMA (same nest as smax) ----
        f32x4 Sacc[2][4];
        #pragma unroll
        for (int mt = 0; mt < 2; ++mt)
            #pragma unroll
            for (int nt = 0; nt < 4; ++nt)
                Sacc[mt][nt] = (f32x4){0.f, 0.f, 0.f, 0.f};
        #pragma unroll
        for (int mt = 0; mt < 2; ++mt)
            #pragma unroll
            for (int ks = 0; ks < 2; ++ks)
                #pragma unroll
                for (int nt = 0; nt < 4; ++nt)
                    Sacc[mt][nt] = __builtin_amdgcn_mfma_f32_16x16x32_f16(
                        kf[mt][ks], qf[nt][ks], Sacc[mt][nt], 0, 0, 0);

        // ---- softmax: P = exp2(S - M[n]) <= 1, fp16, straight to LDS ----
        #pragma unroll
        for (int mt = 0; mt < 2; ++mt)
            #pragma unroll
            for (int nt = 0; nt < 4; ++nt) {
                float p0 = __builtin_amdgcn_exp2f(Sacc[mt][nt][0] - Mn[nt]);
                float p1 = __builtin_amdgcn_exp2f(Sacc[mt][nt][1] - Mn[nt]);
                float p2 = __builtin_amdgcn_exp2f(Sacc[mt][nt][2] - Mn[nt]);
                float p3 = __builtin_amdgcn_exp2f(Sacc[mt][nt][3] - Mn[nt]);
                Li[nt] += (p0 + p1) + (p2 + p3);
                uint2 pk2;
                pk2.x = pk2h(p0, p1);
                pk2.y = pk2h(p2, p3);
                *reinterpret_cast<uint2*>(
                    &PT[buf][(nt * 16 + lq) * PTS + w * 32 + mt * 16 + quad * 4]) = pk2;
            }
        __syncthreads();   // the ONLY barrier: P(it) visible; nothing in flight

        // ---- post-barrier: issue K(it+1), then PV over 128 m ----
        const int itk = (it < 31) ? it + 1 : 31;
        #pragma unroll
        for (int mt = 0; mt < 2; ++mt)
            #pragma unroll
            for (int ks = 0; ks < 2; ++ks)
                kf[mt][ks] = ldg_fragh(Kb + (itk * 128 + w * 32 + mt * 16 + lq) * HID
                                          + ks * 32 + quad * 8);

        h16x8 vf[2][4];
        #pragma unroll
        for (int rt = 0; rt < 4; ++rt)
            vf[0][rt] = ldg_fragh(Vb + (size_t)(w * 64 + rt * 16 + lq) * NPIX
                                     + m0 + quad * 8);
        #pragma unroll
        for (int ks = 0; ks < 4; ++ks) {
            h16x8 pf[4];
            #pragma unroll
            for (int ct = 0; ct < 4; ++ct)
                pf[ct] = lds_fragh(&PT[buf][(ct * 16 + lq) * PTS + ks * 32 + quad * 8]);
            if (ks < 3) {
                #pragma unroll
                for (int rt = 0; rt < 4; ++rt)
                    vf[(ks + 1) & 1][rt] = ldg_fragh(
                        Vb + (size_t)(w * 64 + rt * 16 + lq) * NPIX
                           + m0 + (ks + 1) * 32 + quad * 8);
            }
            #pragma unroll
            for (int rt = 0; rt < 4; ++rt)
                #pragma unroll
                for (int ct = 0; ct < 4; ++ct)
                    Oacc[rt][ct] = __builtin_amdgcn_mfma_f32_16x16x32_f16(
                        vf[ks & 1][rt], pf[ct], Oacc[rt][ct], 0, 0, 0);
        }
    }

    // ---- epilogue: merge per-wave/per-quad L, then out = xq + g*O/L ----
    #pragma unroll
    for (int nt = 0; nt < 4; ++nt) {
        Li[nt] += __shfl_xor(Li[nt], 16);
        Li[nt] += __shfl_xor(Li[nt], 32);
    }
    Lsh[w][quad * 16 + lq] = sel4(Li[0], Li[1], Li[2], Li[3], quad);
    __syncthreads();

    float inv[4];
    #pragma unroll
    for (int nt = 0; nt < 4; ++nt) {
        int i = nt * 16 + lq;
        inv[nt] = 1.0f / ((Lsh[0][i] + Lsh[1][i]) + (Lsh[2][i] + Lsh[3][i]));
    }

    const float* xq = d ? x2 : x1;
    const float gm = gamma[0];

    #pragma unroll
    for (int rt = 0; rt < 4; ++rt)
        #pragma unroll
        for (int ct = 0; ct < 4; ++ct)
            #pragma unroll
            for (int rg = 0; rg < 4; ++rg) {
                int c = w * 64 + rt * 16 + quad * 4 + rg;
                int nn = n0 + ct * 16 + lq;
                size_t src = (size_t)(b * CCH + c) * NPIX + nn;
                size_t dst = (size_t)(db * CCH + c) * NPIX + nn;
                out[dst] = xq[src] + gm * Oacc[rt][ct][rg] * inv[ct];
            }
}

// ---------------------------------------------------------------------------
extern "C" void kernel_launch(void* const* d_in, const int* in_sizes, int n_in,
                              void* d_out, int out_size, void* d_ws, size_t ws_size,
                              hipStream_t stream) {
    (void)in_sizes; (void)n_in; (void)out_size; (void)ws_size;
    const float* x1 = (const float*)d_in[0];
    const float* x2 = (const float*)d_in[1];
    const float* Wq = (const float*)d_in[2];
    const float* bq = (const float*)d_in[3];
    const float* Wk = (const float*)d_in[4];
    const float* bk = (const float*)d_in[5];
    const float* Wv = (const float*)d_in[6];
    const float* bv = (const float*)d_in[7];
    const float* gm = (const float*)d_in[8];
    float* out = (float*)d_out;

    // ws (u16 elems): Qf 2.1M | Kf 2.1M | Vt 8.4M | Wg 98304, then Mg fp32 32768
    unsigned short* ws = (unsigned short*)d_ws;
    unsigned short* Qf = ws;
    unsigned short* Kf = Qf + (size_t)2097152;
    unsigned short* Vt = Kf + (size_t)2097152;
    unsigned short* Wg = Vt + (size_t)8388608;
    float* Mg = (float*)(Wg + 98304);

    wcvt_kernel<<<dim3(96), dim3(256), 0, stream>>>(Wq, Wk, Wv, Wg);
    proj_kernel<<<dim3(1024), dim3(256), 0, stream>>>(
        x1, x2, Wg, bq, bk, bv, Qf, Kf, Vt);
    smax_kernel<<<dim3(512), dim3(256), 0, stream>>>(Qf, Kf, Mg);
    attn_kernel<<<dim3(512), dim3(256), 0, stream>>>(
        x1, x2, Qf, Kf, Vt, Mg, gm, out);
}

// Round 8
// 312.556 us; speedup vs baseline: 6.6602x; 6.6602x over previous
//
#include <hip/hip_runtime.h>
#include <hip/hip_bf16.h>

#define NPIX 4096
#define CCH  256
#define HID  64
#define BAT  4
#define XSTR 264    // proj LDS row stride (halfs)
#define PTS  136    // attn P-tile row stride (halfs): 16B-aligned rows

using f32x4 = __attribute__((ext_vector_type(4))) float;
using h16x8 = __attribute__((ext_vector_type(8))) _Float16;
using u16x4 = __attribute__((ext_vector_type(4))) unsigned short;

#define L2E 1.44269504088896340736f

__device__ __forceinline__ unsigned short f2h(float f) {
    _Float16 h = (_Float16)f;
    return __builtin_bit_cast(unsigned short, h);
}
__device__ __forceinline__ h16x8 ldg_fragh(const unsigned short* p) {
    uint4 v = *reinterpret_cast<const uint4*>(p);
    return __builtin_bit_cast(h16x8, v);
}
__device__ __forceinline__ h16x8 lds_fragh(const unsigned short* p) {
    return *reinterpret_cast<const h16x8*>(p);
}
__device__ __forceinline__ unsigned int pk2h(float a, float b) {
    auto t = __builtin_amdgcn_cvt_pkrtz(a, b);   // <2 x half>, RTZ
    return __builtin_bit_cast(unsigned int, t);
}
__device__ __forceinline__ float sel4(float a0, float a1, float a2, float a3, int q) {
    float x = (q & 1) ? a1 : a0;
    float y = (q & 1) ? a3 : a2;
    return (q & 2) ? y : x;
}

// ---------------------------------------------------------------------------
// W conversion -> row-major [384][256] fp16. Rows 0-63: Wq pre-scaled by
// log2(e) (softmax uses exp2), 64-127: Wk, 128-383: Wv.
// ---------------------------------------------------------------------------
__global__ __launch_bounds__(256, 1) void wcvt_kernel(
    const float* __restrict__ Wq, const float* __restrict__ Wk,
    const float* __restrict__ Wv, unsigned short* __restrict__ Wg)
{
    int idx = (blockIdx.x * 256 + threadIdx.x) * 4;
    int r = idx >> 8, c = idx & 255;
    const float* src = (r < 64)  ? (Wq + r * CCH + c)
                     : (r < 128) ? (Wk + (r - 64) * CCH + c)
                                 : (Wv + (r - 128) * CCH + c);
    float sc = (r < 64) ? L2E : 1.0f;
    float4 v4 = *reinterpret_cast<const float4*>(src);
    u16x4 hv;
    hv[0] = f2h(v4.x * sc); hv[1] = f2h(v4.y * sc);
    hv[2] = f2h(v4.z * sc); hv[3] = f2h(v4.w * sc);
    *reinterpret_cast<u16x4*>(Wg + idx) = hv;
}

// ---------------------------------------------------------------------------
// fp16 MFMA projection (round-5-proven numerics/stores, W dbuf kept).
// Q/K fp16 [n][h]; V fp16 [c][n].
// ---------------------------------------------------------------------------
__global__ __launch_bounds__(256, 2) void proj_kernel(
    const float* __restrict__ x1, const float* __restrict__ x2,
    const unsigned short* __restrict__ Wg,
    const float* __restrict__ bq, const float* __restrict__ bk,
    const float* __restrict__ bv,
    unsigned short* __restrict__ Qf, unsigned short* __restrict__ Kf,
    unsigned short* __restrict__ Vt)
{
    __shared__ unsigned short xs[32][XSTR];
    __shared__ unsigned short scratch[4][256];

    const int Lb = blockIdx.x;
    const int sb = Lb & 7;              // XCD-locality swizzle
    const int tile = Lb >> 3;
    const int s = sb >> 2, b = sb & 3;
    const float* x = s ? x2 : x1;
    const int n0 = tile * 32;
    const int t = threadIdx.x;
    const int lane = t & 63;
    const int w = __builtin_amdgcn_readfirstlane(t >> 6);
    const int quad = lane >> 4, lq = lane & 15;

    // stage x^T fp16 into LDS
    {
        const int n = t & 31;
        const int g = t >> 5;
        const float* xb = x + (size_t)(b * CCH) * NPIX + n0;
        #pragma unroll
        for (int i = 0; i < 8; ++i) {
            int c0 = g * 4 + i * 32;
            u16x4 hv;
            #pragma unroll
            for (int j = 0; j < 4; ++j)
                hv[j] = f2h(xb[(size_t)(c0 + j) * NPIX + n]);
            *reinterpret_cast<u16x4*>(&xs[n][c0]) = hv;
        }
    }
    __syncthreads();

    // hoist x fragments (both ntiles, full K=256)
    h16x8 xf[2][8];
    #pragma unroll
    for (int nt = 0; nt < 2; ++nt)
        #pragma unroll
        for (int ks = 0; ks < 8; ++ks)
            xf[nt][ks] = lds_fragh(&xs[nt * 16 + lq][ks * 32 + quad * 8]);

    const int sbN = (s * BAT + b) * NPIX;
    const int sbC = (s * BAT + b) * CCH;
    unsigned short* sc = scratch[w];

    // W fragment double-buffer (indices compile-time: hloop unrolled)
    h16x8 wf[2][8];
    {
        const unsigned short* wp = Wg + (size_t)((w * 6) * 16 + lq) * CCH + quad * 8;
        #pragma unroll
        for (int ks = 0; ks < 8; ++ks) wf[0][ks] = ldg_fragh(wp + ks * 32);
    }

    #pragma unroll
    for (int hloop = 0; hloop < 6; ++hloop) {
        const int cur = hloop & 1;
        const int idx = w * 6 + hloop;                  // wave-uniform, 0..23
        const int kind = idx < 4 ? 0 : (idx < 8 ? 1 : 2);

        if (hloop < 5) {
            const unsigned short* wp = Wg + (size_t)((idx + 1) * 16 + lq) * CCH + quad * 8;
            #pragma unroll
            for (int ks = 0; ks < 8; ++ks) wf[cur ^ 1][ks] = ldg_fragh(wp + ks * 32);
        }

        #pragma unroll
        for (int nt = 0; nt < 2; ++nt) {
            f32x4 acc = (f32x4){0.f, 0.f, 0.f, 0.f};
            if (kind == 2) {
                #pragma unroll
                for (int ks = 0; ks < 8; ++ks)
                    acc = __builtin_amdgcn_mfma_f32_16x16x32_f16(wf[cur][ks], xf[nt][ks], acc, 0, 0, 0);
                // D[c][n] -> scratch -> coalesced fp16 store
                int cbase = (idx - 8) * 16;
                #pragma unroll
                for (int reg = 0; reg < 4; ++reg)
                    sc[(quad * 4 + reg) * 16 + lq] = f2h(acc[reg] + bv[cbase + quad * 4 + reg]);
                int rl = lane >> 2, c0 = (lane & 3) * 4;
                __builtin_amdgcn_s_waitcnt(0);   // cross-lane LDS RAW (round-5-proven)
                unsigned long long v = *reinterpret_cast<const unsigned long long*>(&sc[rl * 16 + c0]);
                *reinterpret_cast<unsigned long long*>(
                    &Vt[(size_t)(sbC + cbase + rl) * NPIX + n0 + nt * 16 + c0]) = v;
            } else {
                #pragma unroll
                for (int ks = 0; ks < 8; ++ks)
                    acc = __builtin_amdgcn_mfma_f32_16x16x32_f16(xf[nt][ks], wf[cur][ks], acc, 0, 0, 0);
                // D[n][h] -> scratch -> coalesced fp16 store
                unsigned short* dq = (kind ? Kf : Qf);
                const float* bias = (kind ? bk : bq);
                int hbase = (kind ? (idx - 4) : idx) * 16;
                float bb = bias[hbase + lq] * (kind ? 1.0f : L2E);
                #pragma unroll
                for (int reg = 0; reg < 4; ++reg)
                    sc[(quad * 4 + reg) * 16 + lq] = f2h(acc[reg] + bb);
                int rl = lane >> 2, h0 = (lane & 3) * 4;
                __builtin_amdgcn_s_waitcnt(0);
                unsigned long long v = *reinterpret_cast<const unsigned long long*>(&sc[rl * 16 + h0]);
                *reinterpret_cast<unsigned long long*>(
                    &dq[(size_t)(sbN + n0 + nt * 16 + rl) * HID + hbase + h0]) = v;
            }
        }
    }
}

// ---------------------------------------------------------------------------
// Score-max kernel: Mg[db][n] = max_m S'[n][m]. IDENTICAL MFMA nest to attn's
// S-phase (bitwise-equal S). v8 fix: manual 2x-unrolled ping-pong with two
// NAMED K buffers so all register-array indices are compile-time constants
// (v7's kf[it&1] was demoted to scratch -> 1866us at MfmaUtil 0.4%).
// ---------------------------------------------------------------------------
__global__ __launch_bounds__(256, 2) void smax_kernel(
    const unsigned short* __restrict__ Qf, const unsigned short* __restrict__ Kf,
    float* __restrict__ Mg)
{
    __shared__ float Msh[4][64];

    const int Lb = blockIdx.x;
    const int g = Lb & 7;
    const int ntile = Lb >> 3;
    const int d = g >> 2, b = g & 3;
    const int db = d * BAT + b;
    const int s = d, r = 1 - d;
    const int n0 = ntile * 64;

    const int t = threadIdx.x;
    const int lane = t & 63;
    const int w = __builtin_amdgcn_readfirstlane(t >> 6);
    const int quad = lane >> 4, lq = lane & 15;

    const unsigned short* Qb = Qf + (size_t)(s * BAT + b) * NPIX * HID;
    const unsigned short* Kb = Kf + (size_t)(r * BAT + b) * NPIX * HID;

    h16x8 qf[4][2];
    #pragma unroll
    for (int nt = 0; nt < 4; ++nt)
        #pragma unroll
        for (int ks = 0; ks < 2; ++ks)
            qf[nt][ks] = ldg_fragh(Qb + (n0 + nt * 16 + lq) * HID + ks * 32 + quad * 8);

    float mx[4] = {-3.0e38f, -3.0e38f, -3.0e38f, -3.0e38f};

    h16x8 kfA[2][2], kfB[2][2];

    // load(it) into a named buffer; step(buf): S-MFMA nest + fmax
#define SMAX_LOAD(BUF, IT)                                                      \
    {                                                                           \
        _Pragma("unroll")                                                       \
        for (int mt = 0; mt < 2; ++mt) {                                        \
            _Pragma("unroll")                                                   \
            for (int ks = 0; ks < 2; ++ks)                                      \
                BUF[mt][ks] = ldg_fragh(                                        \
                    Kb + ((IT) * 128 + w * 32 + mt * 16 + lq) * HID             \
                       + ks * 32 + quad * 8);                                   \
        }                                                                       \
    }
#define SMAX_STEP(BUF)                                                          \
    {                                                                           \
        f32x4 Sacc[2][4];                                                       \
        _Pragma("unroll")                                                       \
        for (int mt = 0; mt < 2; ++mt) {                                        \
            _Pragma("unroll")                                                   \
            for (int nt = 0; nt < 4; ++nt)                                      \
                Sacc[mt][nt] = (f32x4){0.f, 0.f, 0.f, 0.f};                     \
        }                                                                       \
        _Pragma("unroll")                                                       \
        for (int mt = 0; mt < 2; ++mt) {                                        \
            _Pragma("unroll")                                                   \
            for (int ks = 0; ks < 2; ++ks) {                                    \
                _Pragma("unroll")                                               \
                for (int nt = 0; nt < 4; ++nt)                                  \
                    Sacc[mt][nt] = __builtin_amdgcn_mfma_f32_16x16x32_f16(      \
                        BUF[mt][ks], qf[nt][ks], Sacc[mt][nt], 0, 0, 0);        \
            }                                                                   \
        }                                                                       \
        _Pragma("unroll")                                                       \
        for (int mt = 0; mt < 2; ++mt) {                                        \
            _Pragma("unroll")                                                   \
            for (int nt = 0; nt < 4; ++nt)                                      \
                mx[nt] = fmaxf(mx[nt],                                          \
                    fmaxf(fmaxf(Sacc[mt][nt][0], Sacc[mt][nt][1]),              \
                          fmaxf(Sacc[mt][nt][2], Sacc[mt][nt][3])));            \
        }                                                                       \
    }

    SMAX_LOAD(kfA, 0)
    for (int it = 0; it < 32; it += 2) {
        if (it + 1 < 32) SMAX_LOAD(kfB, it + 1)
        SMAX_STEP(kfA)
        if (it + 2 < 32) SMAX_LOAD(kfA, it + 2)
        SMAX_STEP(kfB)
    }
#undef SMAX_LOAD
#undef SMAX_STEP

    #pragma unroll
    for (int nt = 0; nt < 4; ++nt) {
        mx[nt] = fmaxf(mx[nt], __shfl_xor(mx[nt], 16));
        mx[nt] = fmaxf(mx[nt], __shfl_xor(mx[nt], 32));
    }
    Msh[w][quad * 16 + lq] = sel4(mx[0], mx[1], mx[2], mx[3], quad);
    __syncthreads();

    if (t < 64) {
        float m = fmaxf(fmaxf(Msh[0][t], Msh[1][t]), fmaxf(Msh[2][t], Msh[3][t]));
        Mg[(size_t)db * NPIX + n0 + t] = m;
    }
}

// ---------------------------------------------------------------------------
// Flash cross-attention v7 (unchanged): P = exp2(S - M[n]) <= 1 via
// precomputed M. One barrier per 128-m iter; K/V loads strictly post-barrier.
// ---------------------------------------------------------------------------
__global__ __launch_bounds__(256, 2) void attn_kernel(
    const float* __restrict__ x1, const float* __restrict__ x2,
    const unsigned short* __restrict__ Qf, const unsigned short* __restrict__ Kf,
    const unsigned short* __restrict__ Vt,
    const float* __restrict__ Mg, const float* __restrict__ gamma,
    float* __restrict__ out)
{
    __shared__ unsigned short PT[2][64 * PTS];   // P^T [n=64][m=128], fp16, dbuf
    __shared__ float Lsh[4][64];

    const int Lb = blockIdx.x;
    const int g = Lb & 7;                        // XCD-locality swizzle
    const int ntile = Lb >> 3;
    const int d = g >> 2, b = g & 3;
    const int db = d * BAT + b;
    const int s = d, r = 1 - d;
    const int n0 = ntile * 64;

    const int t = threadIdx.x;
    const int lane = t & 63;
    const int w = __builtin_amdgcn_readfirstlane(t >> 6);
    const int quad = lane >> 4, lq = lane & 15;

    const unsigned short* Qb = Qf + (size_t)(s * BAT + b) * NPIX * HID;
    const unsigned short* Kb = Kf + (size_t)(r * BAT + b) * NPIX * HID;
    const unsigned short* Vb = Vt + (size_t)(r * BAT + b) * CCH * NPIX;

    // per-column max (exp2 units), from smax_kernel
    float Mn[4];
    #pragma unroll
    for (int nt = 0; nt < 4; ++nt)
        Mn[nt] = Mg[(size_t)db * NPIX + n0 + nt * 16 + lq];

    // Q fragments, persistent (B-frags)
    h16x8 qf[4][2];
    #pragma unroll
    for (int nt = 0; nt < 4; ++nt)
        #pragma unroll
        for (int ks = 0; ks < 2; ++ks)
            qf[nt][ks] = ldg_fragh(Qb + (n0 + nt * 16 + lq) * HID + ks * 32 + quad * 8);

    f32x4 Oacc[4][4];
    #pragma unroll
    for (int rt = 0; rt < 4; ++rt)
        #pragma unroll
        for (int ct = 0; ct < 4; ++ct)
            Oacc[rt][ct] = (f32x4){0.f, 0.f, 0.f, 0.f};

    float Li[4] = {0.f, 0.f, 0.f, 0.f};

    // K(0) fragments (wave owns 32 m-rows per 128-m iter)
    h16x8 kf[2][2];
    #pragma unroll
    for (int mt = 0; mt < 2; ++mt)
        #pragma unroll
        for (int ks = 0; ks < 2; ++ks)
            kf[mt][ks] = ldg_fragh(Kb + (w * 32 + mt * 16 + lq) * HID + ks * 32 + quad * 8);

    for (int it = 0; it < 32; ++it) {
        const int buf = it & 1;
        const int m0 = it * 128;

        // ---- S phase (same nest as smax) ----
        f32x4 Sacc[2][4];
        #pragma unroll
        for (int mt = 0; mt < 2; ++mt)
            #pragma unroll
            for (int nt = 0; nt < 4; ++nt)
                Sacc[mt][nt] = (f32x4){0.f, 0.f, 0.f, 0.f};
        #pragma unroll
        for (int mt = 0; mt < 2; ++mt)
            #pragma unroll
            for (int ks = 0; ks < 2; ++ks)
                #pragma unroll
                for (int nt = 0; nt < 4; ++nt)
                    Sacc[mt][nt] = __builtin_amdgcn_mfma_f32_16x16x32_f16(
                        kf[mt][ks], qf[nt][ks], Sacc[mt][nt], 0, 0, 0);

        // ---- softmax: P = exp2(S - M[n]) <= 1, fp16, straight to LDS ----
        #pragma unroll
        for (int mt = 0; mt < 2; ++mt)
            #pragma unroll
            for (int nt = 0; nt < 4; ++nt) {
                float p0 = __builtin_amdgcn_exp2f(Sacc[mt][nt][0] - Mn[nt]);
                float p1 = __builtin_amdgcn_exp2f(Sacc[mt][nt][1] - Mn[nt]);
                float p2 = __builtin_amdgcn_exp2f(Sacc[mt][nt][2] - Mn[nt]);
                float p3 = __builtin_amdgcn_exp2f(Sacc[mt][nt][3] - Mn[nt]);
                Li[nt] += (p0 + p1) + (p2 + p3);
                uint2 pk2;
                pk2.x = pk2h(p0, p1);
                pk2.y = pk2h(p2, p3);
                *reinterpret_cast<uint2*>(
                    &PT[buf][(nt * 16 + lq) * PTS + w * 32 + mt * 16 + quad * 4]) = pk2;
            }
        __syncthreads();   // the ONLY barrier: P(it) visible; nothing in flight

        // ---- post-barrier: issue K(it+1), then PV over 128 m ----
        const int itk = (it < 31) ? it + 1 : 31;
        #pragma unroll
        for (int mt = 0; mt < 2; ++mt)
            #pragma unroll
            for (int ks = 0; ks < 2; ++ks)
                kf[mt][ks] = ldg_fragh(Kb + (itk * 128 + w * 32 + mt * 16 + lq) * HID
                                          + ks * 32 + quad * 8);

        h16x8 vf[2][4];
        #pragma unroll
        for (int rt = 0; rt < 4; ++rt)
            vf[0][rt] = ldg_fragh(Vb + (size_t)(w * 64 + rt * 16 + lq) * NPIX
                                     + m0 + quad * 8);
        #pragma unroll
        for (int ks = 0; ks < 4; ++ks) {
            h16x8 pf[4];
            #pragma unroll
            for (int ct = 0; ct < 4; ++ct)
                pf[ct] = lds_fragh(&PT[buf][(ct * 16 + lq) * PTS + ks * 32 + quad * 8]);
            if (ks < 3) {
                #pragma unroll
                for (int rt = 0; rt < 4; ++rt)
                    vf[(ks + 1) & 1][rt] = ldg_fragh(
                        Vb + (size_t)(w * 64 + rt * 16 + lq) * NPIX
                           + m0 + (ks + 1) * 32 + quad * 8);
            }
            #pragma unroll
            for (int rt = 0; rt < 4; ++rt)
                #pragma unroll
                for (int ct = 0; ct < 4; ++ct)
                    Oacc[rt][ct] = __builtin_amdgcn_mfma_f32_16x16x32_f16(
                        vf[ks & 1][rt], pf[ct], Oacc[rt][ct], 0, 0, 0);
        }
    }

    // ---- epilogue: merge per-wave/per-quad L, then out = xq + g*O/L ----
    #pragma unroll
    for (int nt = 0; nt < 4; ++nt) {
        Li[nt] += __shfl_xor(Li[nt], 16);
        Li[nt] += __shfl_xor(Li[nt], 32);
    }
    Lsh[w][quad * 16 + lq] = sel4(Li[0], Li[1], Li[2], Li[3], quad);
    __syncthreads();

    float inv[4];
    #pragma unroll
    for (int nt = 0; nt < 4; ++nt) {
        int i = nt * 16 + lq;
        inv[nt] = 1.0f / ((Lsh[0][i] + Lsh[1][i]) + (Lsh[2][i] + Lsh[3][i]));
    }

    const float* xq = d ? x2 : x1;
    const float gm = gamma[0];

    #pragma unroll
    for (int rt = 0; rt < 4; ++rt)
        #pragma unroll
        for (int ct = 0; ct < 4; ++ct)
            #pragma unroll
            for (int rg = 0; rg < 4; ++rg) {
                int c = w * 64 + rt * 16 + quad * 4 + rg;
                int nn = n0 + ct * 16 + lq;
                size_t src = (size_t)(b * CCH + c) * NPIX + nn;
                size_t dst = (size_t)(db * CCH + c) * NPIX + nn;
                out[dst] = xq[src] + gm * Oacc[rt][ct][rg] * inv[ct];
            }
}

// ---------------------------------------------------------------------------
extern "C" void kernel_launch(void* const* d_in, const int* in_sizes, int n_in,
                              void* d_out, int out_size, void* d_ws, size_t ws_size,
                              hipStream_t stream) {
    (void)in_sizes; (void)n_in; (void)out_size; (void)ws_size;
    const float* x1 = (const float*)d_in[0];
    const float* x2 = (const float*)d_in[1];
    const float* Wq = (const float*)d_in[2];
    const float* bq = (const float*)d_in[3];
    const float* Wk = (const float*)d_in[4];
    const float* bk = (const float*)d_in[5];
    const float* Wv = (const float*)d_in[6];
    const float* bv = (const float*)d_in[7];
    const float* gm = (const float*)d_in[8];
    float* out = (float*)d_out;

    // ws (u16 elems): Qf 2.1M | Kf 2.1M | Vt 8.4M | Wg 98304, then Mg fp32 32768
    unsigned short* ws = (unsigned short*)d_ws;
    unsigned short* Qf = ws;
    unsigned short* Kf = Qf + (size_t)2097152;
    unsigned short* Vt = Kf + (size_t)2097152;
    unsigned short* Wg = Vt + (size_t)8388608;
    float* Mg = (float*)(Wg + 98304);

    wcvt_kernel<<<dim3(96), dim3(256), 0, stream>>>(Wq, Wk, Wv, Wg);
    proj_kernel<<<dim3(1024), dim3(256), 0, stream>>>(
        x1, x2, Wg, bq, bk, bv, Qf, Kf, Vt);
    smax_kernel<<<dim3(512), dim3(256), 0, stream>>>(Qf, Kf, Mg);
    attn_kernel<<<dim3(512), dim3(256), 0, stream>>>(
        x1, x2, Qf, Kf, Vt, Mg, gm, out);
}

// Round 9
// 304.105 us; speedup vs baseline: 6.8453x; 1.0278x over previous
//
#include <hip/hip_runtime.h>
#include <hip/hip_bf16.h>

#define NPIX 4096
#define CCH  256
#define HID  64
#define BAT  4
#define XSTR 264    // proj LDS row stride (halfs)
#define PTS  136    // attn P-tile row stride (halfs): 16B-aligned rows

using f32x4 = __attribute__((ext_vector_type(4))) float;
using h16x8 = __attribute__((ext_vector_type(8))) _Float16;
using u16x4 = __attribute__((ext_vector_type(4))) unsigned short;

#define L2E 1.44269504088896340736f

__device__ __forceinline__ unsigned short f2h(float f) {
    _Float16 h = (_Float16)f;
    return __builtin_bit_cast(unsigned short, h);
}
__device__ __forceinline__ h16x8 ldg_fragh(const unsigned short* p) {
    uint4 v = *reinterpret_cast<const uint4*>(p);
    return __builtin_bit_cast(h16x8, v);
}
__device__ __forceinline__ h16x8 lds_fragh(const unsigned short* p) {
    return *reinterpret_cast<const h16x8*>(p);
}
__device__ __forceinline__ unsigned int pk2h(float a, float b) {
    auto t = __builtin_amdgcn_cvt_pkrtz(a, b);   // <2 x half>, RTZ
    return __builtin_bit_cast(unsigned int, t);
}
__device__ __forceinline__ float sel4(float a0, float a1, float a2, float a3, int q) {
    float x = (q & 1) ? a1 : a0;
    float y = (q & 1) ? a3 : a2;
    return (q & 2) ? y : x;
}

// ---------------------------------------------------------------------------
// W conversion -> row-major [384][256] fp16. Rows 0-63: Wq pre-scaled by
// log2(e) (softmax uses exp2), 64-127: Wk, 128-383: Wv.
// ---------------------------------------------------------------------------
__global__ __launch_bounds__(256, 1) void wcvt_kernel(
    const float* __restrict__ Wq, const float* __restrict__ Wk,
    const float* __restrict__ Wv, unsigned short* __restrict__ Wg)
{
    int idx = (blockIdx.x * 256 + threadIdx.x) * 4;
    int r = idx >> 8, c = idx & 255;
    const float* src = (r < 64)  ? (Wq + r * CCH + c)
                     : (r < 128) ? (Wk + (r - 64) * CCH + c)
                                 : (Wv + (r - 128) * CCH + c);
    float sc = (r < 64) ? L2E : 1.0f;
    float4 v4 = *reinterpret_cast<const float4*>(src);
    u16x4 hv;
    hv[0] = f2h(v4.x * sc); hv[1] = f2h(v4.y * sc);
    hv[2] = f2h(v4.z * sc); hv[3] = f2h(v4.w * sc);
    *reinterpret_cast<u16x4*>(Wg + idx) = hv;
}

// ---------------------------------------------------------------------------
// fp16 MFMA projection v9: operand order chosen so D-tiles land in the
// STORE layout directly (4 consecutive output elems per lane = one 8B
// store). No LDS scratch round-trip, no explicit waitcnts, W dbuf effective.
//  - Q/K: mfma(wf, xf) -> D[h][n]: h = quad*4+reg (contig), n = lq
//         store to [n][h]: one 8B store per lane per tile.
//  - V:   mfma(xf, wf) -> D[n][c]: n = quad*4+reg (contig), c = lq
//         store to [c][n]: one 8B store per lane per tile.
// ---------------------------------------------------------------------------
__global__ __launch_bounds__(256, 2) void proj_kernel(
    const float* __restrict__ x1, const float* __restrict__ x2,
    const unsigned short* __restrict__ Wg,
    const float* __restrict__ bq, const float* __restrict__ bk,
    const float* __restrict__ bv,
    unsigned short* __restrict__ Qf, unsigned short* __restrict__ Kf,
    unsigned short* __restrict__ Vt)
{
    __shared__ unsigned short xs[32][XSTR];

    const int Lb = blockIdx.x;
    const int sb = Lb & 7;              // XCD-locality swizzle
    const int tile = Lb >> 3;
    const int s = sb >> 2, b = sb & 3;
    const float* x = s ? x2 : x1;
    const int n0 = tile * 32;
    const int t = threadIdx.x;
    const int lane = t & 63;
    const int w = __builtin_amdgcn_readfirstlane(t >> 6);
    const int quad = lane >> 4, lq = lane & 15;

    // stage x^T fp16 into LDS
    {
        const int n = t & 31;
        const int g = t >> 5;
        const float* xb = x + (size_t)(b * CCH) * NPIX + n0;
        #pragma unroll
        for (int i = 0; i < 8; ++i) {
            int c0 = g * 4 + i * 32;
            u16x4 hv;
            #pragma unroll
            for (int j = 0; j < 4; ++j)
                hv[j] = f2h(xb[(size_t)(c0 + j) * NPIX + n]);
            *reinterpret_cast<u16x4*>(&xs[n][c0]) = hv;
        }
    }
    __syncthreads();

    // hoist x fragments (both ntiles, full K=256)
    h16x8 xf[2][8];
    #pragma unroll
    for (int nt = 0; nt < 2; ++nt)
        #pragma unroll
        for (int ks = 0; ks < 8; ++ks)
            xf[nt][ks] = lds_fragh(&xs[nt * 16 + lq][ks * 32 + quad * 8]);

    const int sbN = (s * BAT + b) * NPIX;
    const int sbC = (s * BAT + b) * CCH;

    // W fragment double-buffer (hloop unrolled -> compile-time indices)
    h16x8 wf[2][8];
    {
        const unsigned short* wp = Wg + (size_t)((w * 6) * 16 + lq) * CCH + quad * 8;
        #pragma unroll
        for (int ks = 0; ks < 8; ++ks) wf[0][ks] = ldg_fragh(wp + ks * 32);
    }

    #pragma unroll
    for (int hloop = 0; hloop < 6; ++hloop) {
        const int cur = hloop & 1;
        const int idx = w * 6 + hloop;                  // wave-uniform, 0..23
        const int kind = idx < 4 ? 0 : (idx < 8 ? 1 : 2);

        if (hloop < 5) {
            const unsigned short* wp = Wg + (size_t)((idx + 1) * 16 + lq) * CCH + quad * 8;
            #pragma unroll
            for (int ks = 0; ks < 8; ++ks) wf[cur ^ 1][ks] = ldg_fragh(wp + ks * 32);
        }

        if (kind == 2) {
            const int cbase = (idx - 8) * 16;
            const float bbv = bv[cbase + lq];
            #pragma unroll
            for (int nt = 0; nt < 2; ++nt) {
                f32x4 acc = (f32x4){0.f, 0.f, 0.f, 0.f};
                #pragma unroll
                for (int ks = 0; ks < 8; ++ks)
                    acc = __builtin_amdgcn_mfma_f32_16x16x32_f16(xf[nt][ks], wf[cur][ks], acc, 0, 0, 0);
                // D[n][c]: n = quad*4+reg, c = lq -> 8B store along n
                u16x4 pk;
                #pragma unroll
                for (int reg = 0; reg < 4; ++reg) pk[reg] = f2h(acc[reg] + bbv);
                *reinterpret_cast<unsigned long long*>(
                    &Vt[(size_t)(sbC + cbase + lq) * NPIX + n0 + nt * 16 + quad * 4]) =
                    __builtin_bit_cast(unsigned long long, pk);
            }
        } else {
            unsigned short* dq = (kind ? Kf : Qf);
            const float* bias = (kind ? bk : bq);
            const float scl = kind ? 1.0f : L2E;
            const int hbase = (kind ? (idx - 4) : idx) * 16 + quad * 4;
            float bb4[4];
            #pragma unroll
            for (int reg = 0; reg < 4; ++reg) bb4[reg] = bias[hbase + reg] * scl;
            #pragma unroll
            for (int nt = 0; nt < 2; ++nt) {
                f32x4 acc = (f32x4){0.f, 0.f, 0.f, 0.f};
                #pragma unroll
                for (int ks = 0; ks < 8; ++ks)
                    acc = __builtin_amdgcn_mfma_f32_16x16x32_f16(wf[cur][ks], xf[nt][ks], acc, 0, 0, 0);
                // D[h][n]: h = quad*4+reg, n = lq -> 8B store along h
                u16x4 pk;
                #pragma unroll
                for (int reg = 0; reg < 4; ++reg) pk[reg] = f2h(acc[reg] + bb4[reg]);
                *reinterpret_cast<unsigned long long*>(
                    &dq[(size_t)(sbN + n0 + nt * 16 + lq) * HID + hbase]) =
                    __builtin_bit_cast(unsigned long long, pk);
            }
        }
    }
}

// ---------------------------------------------------------------------------
// Score-max kernel (v8-proven): Mg[db][n] = max_m S'[n][m]; named ping-pong
// K buffers (all register-array indices compile-time).
// ---------------------------------------------------------------------------
__global__ __launch_bounds__(256, 2) void smax_kernel(
    const unsigned short* __restrict__ Qf, const unsigned short* __restrict__ Kf,
    float* __restrict__ Mg)
{
    __shared__ float Msh[4][64];

    const int Lb = blockIdx.x;
    const int g = Lb & 7;
    const int ntile = Lb >> 3;
    const int d = g >> 2, b = g & 3;
    const int db = d * BAT + b;
    const int s = d, r = 1 - d;
    const int n0 = ntile * 64;

    const int t = threadIdx.x;
    const int lane = t & 63;
    const int w = __builtin_amdgcn_readfirstlane(t >> 6);
    const int quad = lane >> 4, lq = lane & 15;

    const unsigned short* Qb = Qf + (size_t)(s * BAT + b) * NPIX * HID;
    const unsigned short* Kb = Kf + (size_t)(r * BAT + b) * NPIX * HID;

    h16x8 qf[4][2];
    #pragma unroll
    for (int nt = 0; nt < 4; ++nt)
        #pragma unroll
        for (int ks = 0; ks < 2; ++ks)
            qf[nt][ks] = ldg_fragh(Qb + (n0 + nt * 16 + lq) * HID + ks * 32 + quad * 8);

    float mx[4] = {-3.0e38f, -3.0e38f, -3.0e38f, -3.0e38f};

    h16x8 kfA[2][2], kfB[2][2];

#define SMAX_LOAD(BUF, IT)                                                      \
    {                                                                           \
        _Pragma("unroll")                                                       \
        for (int mt = 0; mt < 2; ++mt) {                                        \
            _Pragma("unroll")                                                   \
            for (int ks = 0; ks < 2; ++ks)                                      \
                BUF[mt][ks] = ldg_fragh(                                        \
                    Kb + ((IT) * 128 + w * 32 + mt * 16 + lq) * HID             \
                       + ks * 32 + quad * 8);                                   \
        }                                                                       \
    }
#define SMAX_STEP(BUF)                                                          \
    {                                                                           \
        f32x4 Sacc[2][4];                                                       \
        _Pragma("unroll")                                                       \
        for (int mt = 0; mt < 2; ++mt) {                                        \
            _Pragma("unroll")                                                   \
            for (int nt = 0; nt < 4; ++nt)                                      \
                Sacc[mt][nt] = (f32x4){0.f, 0.f, 0.f, 0.f};                     \
        }                                                                       \
        _Pragma("unroll")                                                       \
        for (int mt = 0; mt < 2; ++mt) {                                        \
            _Pragma("unroll")                                                   \
            for (int ks = 0; ks < 2; ++ks) {                                    \
                _Pragma("unroll")                                               \
                for (int nt = 0; nt < 4; ++nt)                                  \
                    Sacc[mt][nt] = __builtin_amdgcn_mfma_f32_16x16x32_f16(      \
                        BUF[mt][ks], qf[nt][ks], Sacc[mt][nt], 0, 0, 0);        \
            }                                                                   \
        }                                                                       \
        _Pragma("unroll")                                                       \
        for (int mt = 0; mt < 2; ++mt) {                                        \
            _Pragma("unroll")                                                   \
            for (int nt = 0; nt < 4; ++nt)                                      \
                mx[nt] = fmaxf(mx[nt],                                          \
                    fmaxf(fmaxf(Sacc[mt][nt][0], Sacc[mt][nt][1]),              \
                          fmaxf(Sacc[mt][nt][2], Sacc[mt][nt][3])));            \
        }                                                                       \
    }

    SMAX_LOAD(kfA, 0)
    for (int it = 0; it < 32; it += 2) {
        if (it + 1 < 32) SMAX_LOAD(kfB, it + 1)
        SMAX_STEP(kfA)
        if (it + 2 < 32) SMAX_LOAD(kfA, it + 2)
        SMAX_STEP(kfB)
    }
#undef SMAX_LOAD
#undef SMAX_STEP

    #pragma unroll
    for (int nt = 0; nt < 4; ++nt) {
        mx[nt] = fmaxf(mx[nt], __shfl_xor(mx[nt], 16));
        mx[nt] = fmaxf(mx[nt], __shfl_xor(mx[nt], 32));
    }
    Msh[w][quad * 16 + lq] = sel4(mx[0], mx[1], mx[2], mx[3], quad);
    __syncthreads();

    if (t < 64) {
        float m = fmaxf(fmaxf(Msh[0][t], Msh[1][t]), fmaxf(Msh[2][t], Msh[3][t]));
        Mg[(size_t)db * NPIX + n0 + t] = m;
    }
}

// ---------------------------------------------------------------------------
// Flash cross-attention v9: precomputed-max softmax, one barrier per 128-m
// iter. ALL 16 V-fragments for iter it preloaded into registers right after
// PV(it-1) (~600 cyc slack); K(it+1) issued right after S(it) (exp2 covers
// its latency before the barrier drain). -Mn folded into Sacc init (C cols
// share n=lq). PV phase is pure register+LDS MFMA, no global-load stalls.
// ---------------------------------------------------------------------------
__global__ __launch_bounds__(256, 2) void attn_kernel(
    const float* __restrict__ x1, const float* __restrict__ x2,
    const unsigned short* __restrict__ Qf, const unsigned short* __restrict__ Kf,
    const unsigned short* __restrict__ Vt,
    const float* __restrict__ Mg, const float* __restrict__ gamma,
    float* __restrict__ out)
{
    __shared__ unsigned short PT[2][64 * PTS];   // P^T [n=64][m=128], fp16, dbuf
    __shared__ float Lsh[4][64];

    const int Lb = blockIdx.x;
    const int g = Lb & 7;                        // XCD-locality swizzle
    const int ntile = Lb >> 3;
    const int d = g >> 2, b = g & 3;
    const int db = d * BAT + b;
    const int s = d, r = 1 - d;
    const int n0 = ntile * 64;

    const int t = threadIdx.x;
    const int lane = t & 63;
    const int w = __builtin_amdgcn_readfirstlane(t >> 6);
    const int quad = lane >> 4, lq = lane & 15;

    const unsigned short* Qb = Qf + (size_t)(s * BAT + b) * NPIX * HID;
    const unsigned short* Kb = Kf + (size_t)(r * BAT + b) * NPIX * HID;
    const unsigned short* Vb = Vt + (size_t)(r * BAT + b) * CCH * NPIX;

    // per-column max (exp2 units), from smax_kernel; n = lq per lane
    float Mn[4];
    #pragma unroll
    for (int nt = 0; nt < 4; ++nt)
        Mn[nt] = Mg[(size_t)db * NPIX + n0 + nt * 16 + lq];

    // Q fragments, persistent (B-frags)
    h16x8 qf[4][2];
    #pragma unroll
    for (int nt = 0; nt < 4; ++nt)
        #pragma unroll
        for (int ks = 0; ks < 2; ++ks)
            qf[nt][ks] = ldg_fragh(Qb + (n0 + nt * 16 + lq) * HID + ks * 32 + quad * 8);

    f32x4 Oacc[4][4];
    #pragma unroll
    for (int rt = 0; rt < 4; ++rt)
        #pragma unroll
        for (int ct = 0; ct < 4; ++ct)
            Oacc[rt][ct] = (f32x4){0.f, 0.f, 0.f, 0.f};

    float Li[4] = {0.f, 0.f, 0.f, 0.f};

    // K(0) and V(0) fragments
    h16x8 kf[2][2];
    #pragma unroll
    for (int mt = 0; mt < 2; ++mt)
        #pragma unroll
        for (int ks = 0; ks < 2; ++ks)
            kf[mt][ks] = ldg_fragh(Kb + (w * 32 + mt * 16 + lq) * HID + ks * 32 + quad * 8);

    h16x8 vf[4][4];   // vf[ks][rt], all of iter it's V, register-resident
    #pragma unroll
    for (int ks = 0; ks < 4; ++ks)
        #pragma unroll
        for (int rt = 0; rt < 4; ++rt)
            vf[ks][rt] = ldg_fragh(Vb + (size_t)(w * 64 + rt * 16 + lq) * NPIX
                                      + ks * 32 + quad * 8);

    for (int it = 0; it < 32; ++it) {
        const int buf = it & 1;

        // ---- S phase: Sacc init to -Mn (col n = lq for all 4 C regs) ----
        f32x4 Sacc[2][4];
        #pragma unroll
        for (int mt = 0; mt < 2; ++mt)
            #pragma unroll
            for (int nt = 0; nt < 4; ++nt)
                Sacc[mt][nt] = (f32x4){-Mn[nt], -Mn[nt], -Mn[nt], -Mn[nt]};
        #pragma unroll
        for (int mt = 0; mt < 2; ++mt)
            #pragma unroll
            for (int ks = 0; ks < 2; ++ks)
                #pragma unroll
                for (int nt = 0; nt < 4; ++nt)
                    Sacc[mt][nt] = __builtin_amdgcn_mfma_f32_16x16x32_f16(
                        kf[mt][ks], qf[nt][ks], Sacc[mt][nt], 0, 0, 0);

        // issue K(it+1) now: exp2 (~350 cyc) covers its latency pre-barrier
        const int itk = (it < 31) ? it + 1 : 31;
        #pragma unroll
        for (int mt = 0; mt < 2; ++mt)
            #pragma unroll
            for (int ks = 0; ks < 2; ++ks)
                kf[mt][ks] = ldg_fragh(Kb + (itk * 128 + w * 32 + mt * 16 + lq) * HID
                                          + ks * 32 + quad * 8);

        // ---- softmax: P = exp2(S - M) <= 1, fp16, straight to LDS ----
        #pragma unroll
        for (int mt = 0; mt < 2; ++mt)
            #pragma unroll
            for (int nt = 0; nt < 4; ++nt) {
                float p0 = __builtin_amdgcn_exp2f(Sacc[mt][nt][0]);
                float p1 = __builtin_amdgcn_exp2f(Sacc[mt][nt][1]);
                float p2 = __builtin_amdgcn_exp2f(Sacc[mt][nt][2]);
                float p3 = __builtin_amdgcn_exp2f(Sacc[mt][nt][3]);
                Li[nt] += (p0 + p1) + (p2 + p3);
                uint2 pk2;
                pk2.x = pk2h(p0, p1);
                pk2.y = pk2h(p2, p3);
                *reinterpret_cast<uint2*>(
                    &PT[buf][(nt * 16 + lq) * PTS + w * 32 + mt * 16 + quad * 4]) = pk2;
            }
        __syncthreads();   // the ONLY barrier; K loads complete by now

        // ---- PV: pure register+LDS MFMA over 128 m ----
        #pragma unroll
        for (int ks = 0; ks < 4; ++ks) {
            h16x8 pf[4];
            #pragma unroll
            for (int ct = 0; ct < 4; ++ct)
                pf[ct] = lds_fragh(&PT[buf][(ct * 16 + lq) * PTS + ks * 32 + quad * 8]);
            #pragma unroll
            for (int rt = 0; rt < 4; ++rt)
                #pragma unroll
                for (int ct = 0; ct < 4; ++ct)
                    Oacc[rt][ct] = __builtin_amdgcn_mfma_f32_16x16x32_f16(
                        vf[ks][rt], pf[ct], Oacc[rt][ct], 0, 0, 0);
        }

        // issue V(it+1) now: S(it+1)+exp2 (~600 cyc) covers latency
        const int m0n = ((it < 31) ? it + 1 : 31) * 128;
        #pragma unroll
        for (int ks = 0; ks < 4; ++ks)
            #pragma unroll
            for (int rt = 0; rt < 4; ++rt)
                vf[ks][rt] = ldg_fragh(Vb + (size_t)(w * 64 + rt * 16 + lq) * NPIX
                                          + m0n + ks * 32 + quad * 8);
    }

    // ---- epilogue: merge per-wave/per-quad L, then out = xq + g*O/L ----
    #pragma unroll
    for (int nt = 0; nt < 4; ++nt) {
        Li[nt] += __shfl_xor(Li[nt], 16);
        Li[nt] += __shfl_xor(Li[nt], 32);
    }
    Lsh[w][quad * 16 + lq] = sel4(Li[0], Li[1], Li[2], Li[3], quad);
    __syncthreads();

    float inv[4];
    #pragma unroll
    for (int nt = 0; nt < 4; ++nt) {
        int i = nt * 16 + lq;
        inv[nt] = 1.0f / ((Lsh[0][i] + Lsh[1][i]) + (Lsh[2][i] + Lsh[3][i]));
    }

    const float* xq = d ? x2 : x1;
    const float gm = gamma[0];

    #pragma unroll
    for (int rt = 0; rt < 4; ++rt)
        #pragma unroll
        for (int ct = 0; ct < 4; ++ct)
            #pragma unroll
            for (int rg = 0; rg < 4; ++rg) {
                int c = w * 64 + rt * 16 + quad * 4 + rg;
                int nn = n0 + ct * 16 + lq;
                size_t src = (size_t)(b * CCH + c) * NPIX + nn;
                size_t dst = (size_t)(db * CCH + c) * NPIX + nn;
                out[dst] = xq[src] + gm * Oacc[rt][ct][rg] * inv[ct];
            }
}

// ---------------------------------------------------------------------------
extern "C" void kernel_launch(void* const* d_in, const int* in_sizes, int n_in,
                              void* d_out, int out_size, void* d_ws, size_t ws_size,
                              hipStream_t stream) {
    (void)in_sizes; (void)n_in; (void)out_size; (void)ws_size;
    const float* x1 = (const float*)d_in[0];
    const float* x2 = (const float*)d_in[1];
    const float* Wq = (const float*)d_in[2];
    const float* bq = (const float*)d_in[3];
    const float* Wk = (const float*)d_in[4];
    const float* bk = (const float*)d_in[5];
    const float* Wv = (const float*)d_in[6];
    const float* bv = (const float*)d_in[7];
    const float* gm = (const float*)d_in[8];
    float* out = (float*)d_out;

    // ws (u16 elems): Qf 2.1M | Kf 2.1M | Vt 8.4M | Wg 98304, then Mg fp32 32768
    unsigned short* ws = (unsigned short*)d_ws;
    unsigned short* Qf = ws;
    unsigned short* Kf = Qf + (size_t)2097152;
    unsigned short* Vt = Kf + (size_t)2097152;
    unsigned short* Wg = Vt + (size_t)8388608;
    float* Mg = (float*)(Wg + 98304);

    wcvt_kernel<<<dim3(96), dim3(256), 0, stream>>>(Wq, Wk, Wv, Wg);
    proj_kernel<<<dim3(1024), dim3(256), 0, stream>>>(
        x1, x2, Wg, bq, bk, bv, Qf, Kf, Vt);
    smax_kernel<<<dim3(512), dim3(256), 0, stream>>>(Qf, Kf, Mg);
    attn_kernel<<<dim3(512), dim3(256), 0, stream>>>(
        x1, x2, Qf, Kf, Vt, Mg, gm, out);
}